// Round 6
// baseline (212.676 us; speedup 1.0000x reference)
//
#include <hip/hip_runtime.h>

// VQ codebook argmin via bf16x3-split MFMA GEMM + quantized top-2 + fp32 rescore.
//   x_in: [B=16, EMB=64, CODES=16384] f32 ; E: [1024, 64] f32
//   out0: x_out [B,EMB,CODES] f32 = E[argmin] ; out1: indices as f32
// score = dot(x, E_k) - 0.5*||E_k||^2  (argmax == argmin of dist2)
// Scan computes 16384*(score+128) in the MFMA accumulator directly:
//   A = x * 2^14 (exact), C-init = wsh2[n] = 16384*(h[n]+128).
//
// R12: additive-pipes law (R8..R11 all ~134us regardless of scheduling):
// dur ~ MFMA(50) + LDS(41) + VALU(20) + misc(23). Demand cuts:
//  - Q=64/wave: each wave ingests the full 256KB B-table; halving wave count
//    halves chip LDS-read time (41->20us). R5 precedent: 2 waves/SIMD is fine.
//  - 32x32x16 MFMA: 8.07cyc/32KFLOP vs 4.85/16K => -17% MFMA pipe (50->41.5).
//    24 MFMAs per (64q x 32tok) tile; 2 interleaved acc chains x 2 waves/SIMD.
//  - 256-thr blocks, 68KB LDS, 2 blocks/CU (barriers overlap), bounds(256,2).
// B layout (32x32): lane l of frag ks reads B[k=ks*16+(l>>5)*8+j][col=l&31];
// C/D: col=lane&31, row=(reg&3)+8*(reg>>2)+4*(lane>>5)  [m74/m101].

#define BB 16
#define EMB 64
#define CODES 16384
#define NT 1024
#define NTILES 32        // 32-token tiles
#define CHUNK 4          // tiles per staging epoch (32 KB)
#define EPOCHS (NTILES / CHUNK)
#define QPB 256          // queries per block (4 waves x 64)
#define TILE_B 8192      // bytes per B tile (bh 4K + bl 4K)

typedef __attribute__((ext_vector_type(8))) short s16x8;    // 8 bf16 (4 VGPRs)
typedef __attribute__((ext_vector_type(16))) float f32x16;  // 32x32 MFMA acc
typedef __attribute__((ext_vector_type(4))) int i32x4;
typedef unsigned int u32;

__device__ inline short bf16_hi(float f) { return (short)(__builtin_bit_cast(u32, f) >> 16); }
__device__ inline float hi_part(float f) { return __builtin_bit_cast(float, __builtin_bit_cast(u32, f) & 0xFFFF0000u); }
__device__ inline u32 umax_(u32 a, u32 b) { return a > b ? a : b; }

// Async global->LDS, 16 B/lane; LDS dest = wave-uniform base + lane*16.
__device__ inline void async_copy16(const char* g, char* lds_base_uniform) {
  __builtin_amdgcn_global_load_lds(
      (const __attribute__((address_space(1))) unsigned int*)g,
      (__attribute__((address_space(3))) unsigned int*)(unsigned int)(unsigned long long)lds_base_uniform,
      16, 0, 0);
}

// ws layout:
//   [0, 256K)      : B-fragment table (32 n-tiles x 8192 B: bh 4K | bl 4K)
//   [266240, +4K)  : wsh  = -0.5*||E_n||^2            (epilogue rescore)
//   [270336, +4K)  : wsh2 = 16384*(wsh[n]+128)        (scan C-init)
#define WSE_OFF   0
#define WSH_OFF   266240
#define WSH2_OFF  270336

__global__ __launch_bounds__(256) void vq_prep(const float* __restrict__ E,
                                               char* __restrict__ wsE,
                                               float* __restrict__ wsh,
                                               float* __restrict__ wsh2) {
  const int bid = blockIdx.x, tid = threadIdx.x;
  if (bid < 32) {
    // 8192 tasks: code n (1024) x ks (4) x half (2); each packs 8 bf16 h + 8 l.
    const int gid = bid * 256 + tid;
    const int n = gid >> 3, ks = (gid >> 1) & 3, half = gid & 1;
    const float* ep = E + n * EMB + ks * 16 + half * 8;
    s16x8 hv, lv;
    #pragma unroll
    for (int j = 0; j < 8; ++j) {
      float v = ep[j];
      float hf = hi_part(v);
      hv[j] = bf16_hi(v);
      lv[j] = bf16_hi(v - hf);   // v - hf exact in fp32
    }
    // 32x32 B-frag: lane (half*32 + n&31) of fragment (tile=n>>5, ks).
    char* base = wsE + ((size_t)(n >> 5)) * TILE_B + (size_t)ks * 1024 +
                 (size_t)(half * 32 + (n & 31)) * 16;
    *(i32x4*)(base)        = __builtin_bit_cast(i32x4, hv);
    *(i32x4*)(base + 4096) = __builtin_bit_cast(i32x4, lv);
  } else {
    const int n = (bid - 32) * 256 + tid;
    if (n < NT) {
      const float4* ep = (const float4*)(E + n * EMB);
      float s = 0.f;
      #pragma unroll
      for (int g = 0; g < 16; ++g) { float4 v = ep[g]; s += v.x*v.x + v.y*v.y + v.z*v.z + v.w*v.w; }
      const float h = -0.5f * s;
      wsh[n] = h;
      wsh2[n] = 16384.f * (h + 128.f);
    }
  }
}

#define MFMA32 __builtin_amdgcn_mfma_f32_32x32x16_bf16

#define TOP2(AV, MT)                                                        \
  do {                                                                      \
    _Pragma("unroll")                                                       \
    for (int r = 0; r < 16; ++r) {                                          \
      u32 q = (u32)AV[r];                  /* v_cvt_u32_f32 (trunc) */      \
      u32 key = (q << 10) + inv;                                            \
      u32 k1o = k1[MT][r];                                                  \
      asm("v_med3_u32 %0, %1, %2, %3"                                       \
          : "=v"(k2[MT][r]) : "v"(key), "v"(k1o), "v"(k2[MT][r]));          \
      k1[MT][r] = umax_(key, k1o);                                          \
    }                                                                       \
  } while (0)

// Block = 256 threads (4 waves); wave scans 64 queries; block = 256 queries.
__global__ __launch_bounds__(256, 2) void vq_main(
    const float* __restrict__ x, const float* __restrict__ E,
    const char* __restrict__ wsE, const float* __restrict__ wsh,
    const float* __restrict__ wsh2,
    float* __restrict__ xout, float* __restrict__ iout) {
  __shared__ char smem[2 * CHUNK * TILE_B + 4096];   // 64 KB B staging + 4 KB wsh2
  float* lh = (float*)(smem + 2 * CHUNK * TILE_B);
  const int tid = threadIdx.x;
  const int wave = tid >> 6, lane = tid & 63;
  const int col = lane & 31, half = lane >> 5;
  const int b = blockIdx.y;
  const int c0 = blockIdx.x * QPB;
  const int cw = c0 + wave * 64;

  // Stage wsh2 -> LDS (1024 floats; 256 thr x 16 B) and kick epoch-0 staging.
  ((float4*)lh)[tid] = ((const float4*)wsh2)[tid];
  {
    const char* g = wsE + wave * TILE_B + lane * 16;  // 4 waves x 8 KB = 32 KB epoch
    char* lb = smem + wave * TILE_B;                  // wave-uniform base
    #pragma unroll
    for (int i = 0; i < 8; ++i) async_copy16(g + i * 1024, lb + i * 1024);
  }

  // A fragments (32x32 layout): lane holds A[m = mt*32+col][k = ks*16+half*8+j].
  s16x8 ah[2][4], al[2][4];
  #pragma unroll
  for (int mt = 0; mt < 2; ++mt) {
    #pragma unroll
    for (int ks = 0; ks < 4; ++ks) {
      s16x8 hv, lv;
      #pragma unroll
      for (int j = 0; j < 8; ++j) {
        const int e = ks * 16 + half * 8 + j;
        float v = x[((size_t)b * EMB + e) * CODES + (size_t)(cw + mt * 32 + col)] * 16384.f;
        float hf = hi_part(v);
        hv[j] = bf16_hi(v);
        lv[j] = bf16_hi(v - hf);
      }
      ah[mt][ks] = hv;
      al[mt][ks] = lv;
    }
  }

  // key = (u32)acc << 10 | (1023 - n); larger (1023-n) wins ties => earliest idx.
  u32 k1[2][16], k2[2][16];
  #pragma unroll
  for (int mt = 0; mt < 2; ++mt)
    #pragma unroll
    for (int r = 0; r < 16; ++r) { k1[mt][r] = 0u; k2[mt][r] = 0u; }

  u32 inv = 1023u - (u32)col;

  __syncthreads();   // drains epoch-0 staging (vmcnt) + wsh2 LDS

  for (int c = 0; c < EPOCHS; ++c) {
    if (c < EPOCHS - 1) {                          // async-stage next epoch
      const char* g = wsE + (size_t)(c + 1) * (CHUNK * TILE_B) + wave * TILE_B + lane * 16;
      char* lb = smem + ((c + 1) & 1) * (CHUNK * TILE_B) + wave * TILE_B;
      #pragma unroll
      for (int i = 0; i < 8; ++i) async_copy16(g + i * 1024, lb + i * 1024);
    }

    const char* rb = smem + (c & 1) * (CHUNK * TILE_B) + lane * 16;
    #pragma unroll
    for (int t = 0; t < CHUNK; ++t) {
      const char* p = rb + t * TILE_B;
      const s16x8 bh0 = __builtin_bit_cast(s16x8, *(const i32x4*)(p));
      const s16x8 bh1 = __builtin_bit_cast(s16x8, *(const i32x4*)(p + 1024));
      const s16x8 bh2 = __builtin_bit_cast(s16x8, *(const i32x4*)(p + 2048));
      const s16x8 bh3 = __builtin_bit_cast(s16x8, *(const i32x4*)(p + 3072));
      const s16x8 bl0 = __builtin_bit_cast(s16x8, *(const i32x4*)(p + 4096));
      const s16x8 bl1 = __builtin_bit_cast(s16x8, *(const i32x4*)(p + 5120));
      const s16x8 bl2 = __builtin_bit_cast(s16x8, *(const i32x4*)(p + 6144));
      const s16x8 bl3 = __builtin_bit_cast(s16x8, *(const i32x4*)(p + 7168));
      const float ch = lh[(c * CHUNK + t) * 32 + col];

      f32x16 a0, a1;
      #pragma unroll
      for (int i = 0; i < 16; ++i) { a0[i] = ch; a1[i] = ch; }  // C carries offset

      // hh product (2 interleaved chains: mt0 / mt1)
      a0 = MFMA32(ah[0][0], bh0, a0, 0, 0, 0);  a1 = MFMA32(ah[1][0], bh0, a1, 0, 0, 0);
      a0 = MFMA32(ah[0][1], bh1, a0, 0, 0, 0);  a1 = MFMA32(ah[1][1], bh1, a1, 0, 0, 0);
      a0 = MFMA32(ah[0][2], bh2, a0, 0, 0, 0);  a1 = MFMA32(ah[1][2], bh2, a1, 0, 0, 0);
      a0 = MFMA32(ah[0][3], bh3, a0, 0, 0, 0);  a1 = MFMA32(ah[1][3], bh3, a1, 0, 0, 0);
      // lh product (x_lo * e_hi)
      a0 = MFMA32(al[0][0], bh0, a0, 0, 0, 0);  a1 = MFMA32(al[1][0], bh0, a1, 0, 0, 0);
      a0 = MFMA32(al[0][1], bh1, a0, 0, 0, 0);  a1 = MFMA32(al[1][1], bh1, a1, 0, 0, 0);
      a0 = MFMA32(al[0][2], bh2, a0, 0, 0, 0);  a1 = MFMA32(al[1][2], bh2, a1, 0, 0, 0);
      a0 = MFMA32(al[0][3], bh3, a0, 0, 0, 0);  a1 = MFMA32(al[1][3], bh3, a1, 0, 0, 0);
      // hl product (x_hi * e_lo)
      a0 = MFMA32(ah[0][0], bl0, a0, 0, 0, 0);  a1 = MFMA32(ah[1][0], bl0, a1, 0, 0, 0);
      a0 = MFMA32(ah[0][1], bl1, a0, 0, 0, 0);  a1 = MFMA32(ah[1][1], bl1, a1, 0, 0, 0);
      a0 = MFMA32(ah[0][2], bl2, a0, 0, 0, 0);  a1 = MFMA32(ah[1][2], bl2, a1, 0, 0, 0);
      a0 = MFMA32(ah[0][3], bl3, a0, 0, 0, 0);  a1 = MFMA32(ah[1][3], bl3, a1, 0, 0, 0);

      TOP2(a0, 0);
      TOP2(a1, 1);
      inv -= 32u;
    }
    __syncthreads();   // drains next-epoch staging; protects buffer reuse
  }

  // Merge top-2 across the 32 col-lanes (xor 1..16 stays inside the half).
  uint2* cand = (uint2*)smem;                      // staging LDS now free
  int* idxs = (int*)(smem + 2048);
  #pragma unroll
  for (int mt = 0; mt < 2; ++mt) {
    #pragma unroll
    for (int r = 0; r < 16; ++r) {
      u32 a1k = k1[mt][r], a2k = k2[mt][r];
      #pragma unroll
      for (int m = 1; m <= 16; m <<= 1) {
        u32 r1 = __shfl_xor(a1k, m, 64);
        u32 r2 = __shfl_xor(a2k, m, 64);
        u32 t = a1k < r1 ? a1k : r1;
        a1k = umax_(a1k, r1);
        a2k = umax_(umax_(a2k, r2), t);
      }
      // C/D: local query = wave*64 + mt*32 + (r&3) + 8*(r>>2) + 4*half
      if (col == r)
        cand[wave * 64 + mt * 32 + (r & 3) + 8 * (r >> 2) + 4 * half] =
            make_uint2(a1k, a2k);
    }
  }
  __syncthreads();

  // Rescore: 256 threads, one query each; exact fp32 on both candidates.
  {
    const u32 K1 = cand[tid].x, K2 = cand[tid].y;
    const int i1 = 1023 - (int)(K1 & 1023u);
    const int i2 = 1023 - (int)(K2 & 1023u);
    const float* xq = x + (size_t)b * EMB * CODES + (size_t)(c0 + tid);
    const float4* e1 = (const float4*)(E + i1 * EMB);
    const float4* e2 = (const float4*)(E + i2 * EMB);
    float d10 = 0, d11 = 0, d12 = 0, d13 = 0, d20 = 0, d21 = 0, d22 = 0, d23 = 0;
    #pragma unroll
    for (int g = 0; g < 16; ++g) {
      float4 a = e1[g], c4 = e2[g];
      float x0 = xq[(size_t)(4 * g + 0) * CODES];
      float x1 = xq[(size_t)(4 * g + 1) * CODES];
      float x2 = xq[(size_t)(4 * g + 2) * CODES];
      float x3 = xq[(size_t)(4 * g + 3) * CODES];
      d10 = fmaf(x0, a.x, d10);  d11 = fmaf(x1, a.y, d11);
      d12 = fmaf(x2, a.z, d12);  d13 = fmaf(x3, a.w, d13);
      d20 = fmaf(x0, c4.x, d20); d21 = fmaf(x1, c4.y, d21);
      d22 = fmaf(x2, c4.z, d22); d23 = fmaf(x3, c4.w, d23);
    }
    const float s1 = ((d10 + d11) + (d12 + d13)) + wsh[i1];
    const float s2 = ((d20 + d21) + (d22 + d23)) + wsh[i2];
    const bool take2 = (s2 > s1) || (s2 == s1 && i2 < i1);
    const int idx = take2 ? i2 : i1;
    idxs[tid] = idx;
    iout[(size_t)b * CODES + (size_t)(c0 + tid)] = (float)idx;
  }
  __syncthreads();

  // Output fan-out: 256 threads; thread -> query tid, all 64 e-values.
  {
    const int idx = idxs[tid];
    const float* Er = E + idx * EMB;
    float* xo = xout + (size_t)b * EMB * CODES + (size_t)(c0 + tid);
    #pragma unroll
    for (int e = 0; e < EMB; ++e) xo[(size_t)e * CODES] = Er[e];
  }
}

extern "C" void kernel_launch(void* const* d_in, const int* in_sizes, int n_in,
                              void* d_out, int out_size, void* d_ws, size_t ws_size,
                              hipStream_t stream) {
  const float* x = (const float*)d_in[0];   // [16, 64, 16384]
  const float* E = (const float*)d_in[1];   // [1024, 64]
  float* xout = (float*)d_out;
  float* iout = (float*)d_out + (size_t)BB * EMB * CODES;

  char* wsE  = (char*)d_ws + WSE_OFF;
  float* wsh  = (float*)((char*)d_ws + WSH_OFF);
  float* wsh2 = (float*)((char*)d_ws + WSH2_OFF);

  vq_prep<<<36, 256, 0, stream>>>(E, wsE, wsh, wsh2);
  vq_main<<<dim3(CODES / QPB, BB), 256, 0, stream>>>(x, E, wsE, wsh, wsh2, xout, iout);
}